// Round 4
// baseline (2598.147 us; speedup 1.0000x reference)
//
#include <hip/hip_runtime.h>
#include <hip/hip_bf16.h>

typedef unsigned short u16;
typedef unsigned int   u32;

#define NB 32
#define CC 64
#define TT 300
#define VV 25
#define OO 128
#define TO 150
#define KT 9

typedef short s8v  __attribute__((ext_vector_type(8)));
typedef float f4v  __attribute__((ext_vector_type(4)));

__device__ __forceinline__ float b2f(u16 u){
  union { u32 i; float f; } c; c.i = ((u32)u) << 16; return c.f;
}
__device__ __forceinline__ u16 f2b(float f){
  __hip_bfloat16 h = __float2bfloat16(f);
  return *reinterpret_cast<u16*>(&h);
}
__device__ __forceinline__ void async16(const void* g, void* l){
  __builtin_amdgcn_global_load_lds((const __attribute__((address_space(1))) u32*)g,
                                   (__attribute__((address_space(3))) u32*)l, 16, 0, 0);
}

// ---------------- prep: A_sum (f32) + zero-page + tcn_w repack Wq2[kc][o][64] (bf16) ----------------
__global__ __launch_bounds__(256) void k_prep(const float* __restrict__ Ap, const float* __restrict__ ei,
                                              const float* __restrict__ tw, float* __restrict__ Asum,
                                              float* __restrict__ zbuf, u16* __restrict__ Wq2){
  int idx = blockIdx.x * 256 + threadIdx.x;
  if (idx < VV*VV){
    float s = 0.f;
    for (int p = 0; p < 3; ++p) s += ei[p] * Ap[p*VV*VV + idx];
    Asum[idx] = s;
  }
  if (idx >= 640 && idx < 768) zbuf[idx - 640] = 0.f;   // 512 B zero page for conv halo
  int w = idx - 1024;
  if (w >= 0 && w < 18*OO*64){
    int kc = w >> 13;            // /8192
    int r  = w & 8191;
    int o  = r >> 6;
    int j  = r & 63;
    int k  = kc >> 1;
    int i  = (kc & 1)*64 + j;
    // Wq2[kc][o][j] = tcn_w[o][i][k]
    Wq2[w] = f2b(tw[o*(OO*KT) + i*KT + k]);
  }
}

// ---------------- gcn: per (n,t): LDS-staged reads, agg (K=25), O x C GEMM, LDS-staged writes ----------------
__global__ __launch_bounds__(256) void k_gcn(const float* __restrict__ x, const float* __restrict__ Asum,
                                             const float* __restrict__ gw, const float* __restrict__ gb,
                                             u16* __restrict__ xg){
  __shared__ __align__(16) float xs[CC][28];     // 7168 B, x[n][c][t][:]
  __shared__ __align__(16) float As[VV*VV];      // 2500 B
  __shared__ __align__(16) float aggs[VV][72];   // 7200 B, [w][c]
  __shared__ __align__(16) u16  og[VV*OO];       // 6400 B, out tile (v,o)
  int n = blockIdx.x / TT, t = blockIdx.x % TT;
  int tid = threadIdx.x;

  // coalesced stage of x[n][:,t,:]
  for (int idx = tid; idx < CC*VV; idx += 256){
    int c = idx / VV, v = idx - c*VV;
    xs[c][v] = x[((size_t)(n*CC + c)*TT + t)*VV + v];
  }
  for (int idx = tid; idx < VV*VV; idx += 256) As[idx] = Asum[idx];
  __syncthreads();

  // agg[w][c] = sum_v xs[c][v] * A_sum[v][w], spread over all 256 threads
  for (int idx = tid; idx < CC*VV; idx += 256){
    int c = idx / VV, w = idx - c*VV;
    float acc = 0.f;
    #pragma unroll
    for (int v = 0; v < VV; ++v) acc += xs[c][v] * As[v*VV + w];
    aggs[w][c] = acc;
  }
  __syncthreads();

  // 25x128 GEMM, K=64
  int vq = tid & 7, ot = tid >> 3;
  int nv = (vq == 0) ? 4 : 3;
  float acc[4][4];
  #pragma unroll
  for (int q = 0; q < 4; ++q)
    #pragma unroll
    for (int j = 0; j < 4; ++j) acc[q][j] = 0.f;
  for (int c4 = 0; c4 < CC; c4 += 4){
    float4 a[4];
    for (int j = 0; j < nv; ++j) a[j] = *(const float4*)&aggs[vq + 8*j][c4];
    #pragma unroll
    for (int q = 0; q < 4; ++q){
      int o = ot + q*32;
      float4 g = *(const float4*)&gw[o*CC + c4];
      for (int j = 0; j < nv; ++j)
        acc[q][j] += a[j].x*g.x + a[j].y*g.y + a[j].z*g.z + a[j].w*g.w;
    }
  }
  #pragma unroll
  for (int q = 0; q < 4; ++q){
    int o = ot + q*32;
    float bo = gb[o];
    for (int j = 0; j < nv; ++j){
      int v = vq + 8*j;
      og[v*OO + o] = f2b(acc[q][j] + bo);
    }
  }
  __syncthreads();

  // coalesced copy-out: 1600 consecutive u32
  const u32* ogu = (const u32*)og;
  u32* dst = (u32*)(xg + (size_t)(n*TT + t)*VV*OO);
  for (int idx = tid; idx < VV*OO/2; idx += 256) dst[idx] = ogu[idx];
}

// ---------------- tcn as MFMA implicit GEMM: M=(v*150+t2) per n, N=128 o, K=1152 ----------------
// xt layout: [n][m=v*150+t2][o]
__global__ __launch_bounds__(256) void k_tcnm(const u16* __restrict__ xg, const u16* __restrict__ Wq2,
                                              const float* __restrict__ tb, const u16* __restrict__ zbuf,
                                              u16* __restrict__ xt){
  __shared__ __align__(16) u16 A_lds[128*64];   // 16 KB, rows m, 64 k-elems, XOR-swizzled granules
  __shared__ __align__(16) u16 B_lds[128*64];   // 16 KB, rows o, 64 k-elems, XOR-swizzled granules
  int bx = blockIdx.x;
  int n  = bx / 30;
  int m0 = (bx % 30) * 128;
  int tid = threadIdx.x;
  int lane = tid & 63, wv = tid >> 6;
  int wm = (wv & 1) * 64, wo = (wv >> 1) * 64;
  int lr = lane & 15, lq = lane >> 4;

  // staging precompute: thread handles rows r = it*32 + (tid>>3), granule p = tid&7
  int rlow = tid >> 3;
  int gsrc = (tid & 7) ^ (rlow & 7);            // source granule (XOR swizzle on source)
  int tid16 = tid * 16;                          // LDS dest byte offset (lane-contiguous)
  int  tbase[4]; size_t c0[4]; bool vm[4];
  #pragma unroll
  for (int it = 0; it < 4; ++it){
    int m = m0 + it*32 + rlow;
    vm[it] = (m < 3750);
    int v  = m / TO, t2 = m % TO;
    tbase[it] = 2*t2 - 4;
    c0[it] = (size_t)n*(TT*VV*OO) + (size_t)v*OO + gsrc*8;
  }

  f4v acc[4][4];
  #pragma unroll
  for (int mi = 0; mi < 4; ++mi)
    #pragma unroll
    for (int ni = 0; ni < 4; ++ni) acc[mi][ni] = (f4v)(0.f);

  for (int kc = 0; kc < 18; ++kc){
    int k  = kc >> 1;
    int i0 = (kc & 1) * 64;
    const u16* wbase = Wq2 + kc*8192;
    #pragma unroll
    for (int it = 0; it < 4; ++it){
      int t = tbase[it] + k;
      const u16* ga = (vm[it] && t >= 0 && t < TT)
                      ? xg + c0[it] + (size_t)t*(VV*OO) + i0
                      : zbuf;
      async16(ga, (char*)A_lds + it*4096 + tid16);
      async16(wbase + ((it*32 + rlow)*64 + gsrc*8), (char*)B_lds + it*4096 + tid16);
    }
    __syncthreads();
    #pragma unroll
    for (int ks = 0; ks < 2; ++ks){
      int p = ((ks*4 + lq) ^ (lane & 7)) * 8;    // physical element offset of logical granule
      s8v af[4], bf[4];
      #pragma unroll
      for (int mi = 0; mi < 4; ++mi)
        af[mi] = *(const s8v*)&A_lds[(wm + mi*16 + lr)*64 + p];
      #pragma unroll
      for (int ni = 0; ni < 4; ++ni)
        bf[ni] = *(const s8v*)&B_lds[(wo + ni*16 + lr)*64 + p];
      #pragma unroll
      for (int mi = 0; mi < 4; ++mi)
        #pragma unroll
        for (int ni = 0; ni < 4; ++ni)
          acc[mi][ni] = __builtin_amdgcn_mfma_f32_16x16x32_bf16(af[mi], bf[ni], acc[mi][ni], 0, 0, 0);
    }
    __syncthreads();
  }

  // epilogue: D[m][o], m = m0+wm+mi*16+lq*4+rg, o = wo+ni*16+lr
  float bias[4];
  #pragma unroll
  for (int ni = 0; ni < 4; ++ni) bias[ni] = tb[wo + ni*16 + lr];
  #pragma unroll
  for (int mi = 0; mi < 4; ++mi){
    int mr = m0 + wm + mi*16 + lq*4;
    #pragma unroll
    for (int ni = 0; ni < 4; ++ni){
      int o = wo + ni*16 + lr;
      #pragma unroll
      for (int rg = 0; rg < 4; ++rg){
        int m = mr + rg;
        if (m < 3750)
          xt[((size_t)n*3750 + m)*OO + o] = f2b(acc[mi][ni][rg] + bias[ni]);
      }
    }
  }
}

// ---------------- BN stats, stage 1: per-block partial sums over 480 rows of 128 ----------------
__global__ __launch_bounds__(256) void k_stats1(const u16* __restrict__ xt, float* __restrict__ psum,
                                                float* __restrict__ psq){
  __shared__ float ls[256], lq[256];
  int tid = threadIdx.x;
  int o = tid & 127, rh = tid >> 7;
  int r0 = blockIdx.x * 480;
  float s = 0.f, q = 0.f;
  for (int r = r0 + rh; r < r0 + 480; r += 2){
    float f = b2f(xt[(size_t)r*OO + o]);
    s += f; q += f*f;
  }
  ls[tid] = s; lq[tid] = q;
  __syncthreads();
  if (tid < 128){
    psum[blockIdx.x*128 + o] = ls[tid] + ls[tid + 128];
    psq [blockIdx.x*128 + o] = lq[tid] + lq[tid + 128];
  }
}

// ---------------- BN stats, stage 2: finalize scale/shift per channel ----------------
__global__ __launch_bounds__(128) void k_stats2(const float* __restrict__ psum, const float* __restrict__ psq,
                                                const float* __restrict__ gamma, const float* __restrict__ beta,
                                                float* __restrict__ stats){
  int o = threadIdx.x;
  float s = 0.f, q = 0.f;
  for (int b = 0; b < 250; ++b){ s += psum[b*128 + o]; q += psq[b*128 + o]; }
  const float inv = 1.f / 120000.f;
  float mean = s * inv;
  float var  = q * inv - mean*mean;        // biased, matches jnp.var
  float sc = gamma[o] * rsqrtf(var + 1e-5f);
  stats[o]       = sc;
  stats[128 + o] = beta[o] - mean * sc;
}

// ---------------- final: res GEMM (K=64) + BN affine + relu; LDS-staged coalesced writes ----------------
__global__ __launch_bounds__(256) void k_final(const float* __restrict__ x, const u16* __restrict__ xt,
                                               const float* __restrict__ stats, const float* __restrict__ rw,
                                               const float* __restrict__ rb, float* __restrict__ out){
  __shared__ __align__(16) float xs[VV][72];     // 7200 B
  __shared__ __align__(16) float og[OO*VV];      // 12800 B, out tile (o,v)
  int n = blockIdx.x / TO, t2 = blockIdx.x % TO;
  int tid = threadIdx.x;
  const float* xb = x + (size_t)n*CC*TT*VV + (size_t)(2*t2)*VV;  // x[n][c][2*t2][v]
  for (int idx = tid; idx < CC*VV; idx += 256){
    int c = idx / VV, v = idx - c*VV;
    xs[v][c] = xb[(size_t)c*(TT*VV) + v];
  }
  __syncthreads();
  int vq = tid & 7, ot = tid >> 3;
  int nv = (vq == 0) ? 4 : 3;
  float acc[4][4];
  #pragma unroll
  for (int q = 0; q < 4; ++q)
    #pragma unroll
    for (int j = 0; j < 4; ++j) acc[q][j] = 0.f;
  for (int c4 = 0; c4 < CC; c4 += 4){
    float4 a[4];
    for (int j = 0; j < nv; ++j) a[j] = *(const float4*)&xs[vq + 8*j][c4];
    #pragma unroll
    for (int q = 0; q < 4; ++q){
      int o = ot + q*32;
      float4 g = *(const float4*)&rw[o*CC + c4];
      for (int j = 0; j < nv; ++j)
        acc[q][j] += a[j].x*g.x + a[j].y*g.y + a[j].z*g.z + a[j].w*g.w;
    }
  }
  #pragma unroll
  for (int q = 0; q < 4; ++q){
    int o = ot + q*32;
    float sc = stats[o], sb = stats[128 + o], rbo = rb[o];
    for (int j = 0; j < nv; ++j){
      int v = vq + 8*j;
      // xt layout: [n][m=v*150+t2][o]
      float xtv = b2f(xt[((size_t)n*3750 + (size_t)v*TO + t2)*OO + o]);
      float r = sc*xtv + sb + acc[q][j] + rbo;
      og[o*VV + v] = fmaxf(r, 0.f);
    }
  }
  __syncthreads();
  // staged write: rows of 25 consecutive floats per o
  for (int idx = tid; idx < OO*VV; idx += 256){
    int o = idx / VV, v = idx - o*VV;
    out[((size_t)(n*OO + o)*TO + t2)*VV + v] = og[idx];
  }
}

extern "C" void kernel_launch(void* const* d_in, const int* in_sizes, int n_in,
                              void* d_out, int out_size, void* d_ws, size_t ws_size,
                              hipStream_t stream) {
  const float* x     = (const float*)d_in[0];
  const float* Ap    = (const float*)d_in[1];
  const float* ei    = (const float*)d_in[2];
  const float* gw    = (const float*)d_in[3];
  const float* gb    = (const float*)d_in[4];
  const float* tw    = (const float*)d_in[5];
  const float* tb    = (const float*)d_in[6];
  const float* gamma = (const float*)d_in[7];
  const float* beta  = (const float*)d_in[8];
  const float* rw    = (const float*)d_in[9];
  const float* rb    = (const float*)d_in[10];
  float* out = (float*)d_out;

  char* ws = (char*)d_ws;
  float* Asum  = (float*)ws;                      // 2500 B
  float* zbuf  = (float*)(ws + 2560);             // 512 B zero page
  u16*   Wq2   = (u16*)(ws + 4096);               // 294912 B -> 299008
  float* psum  = (float*)(ws + 299008);           // 128000 B -> 427008
  float* psq   = (float*)(ws + 427008);           // 128000 B -> 555008
  float* stats = (float*)(ws + 555008);           // 1024 B
  u16*   xg    = (u16*)(ws + (1u<<20));           // 61,440,000 B  (N,T,V,O) bf16
  u16*   xt    = (u16*)(ws + 62488576);           // 28,800,000 B  [n][m][o] bf16; total ~91.3 MB

  k_prep  <<<dim3(580),    dim3(256), 0, stream>>>(Ap, ei, tw, Asum, zbuf, Wq2);
  k_gcn   <<<dim3(NB*TT),  dim3(256), 0, stream>>>(x, Asum, gw, gb, xg);
  k_tcnm  <<<dim3(NB*30),  dim3(256), 0, stream>>>(xg, Wq2, tb, (const u16*)zbuf, xt);
  k_stats1<<<dim3(250),    dim3(256), 0, stream>>>(xt, psum, psq);
  k_stats2<<<dim3(1),      dim3(128), 0, stream>>>(psum, psq, gamma, beta, stats);
  k_final <<<dim3(NB*TO),  dim3(256), 0, stream>>>(x, xt, stats, rw, rb, out);
}

// Round 6
// 1194.293 us; speedup vs baseline: 2.1755x; 2.1755x over previous
//
#include <hip/hip_runtime.h>
#include <hip/hip_bf16.h>

typedef unsigned short u16;
typedef unsigned int   u32;

#define NB 32
#define CC 64
#define TT 300
#define VV 25
#define OO 128
#define TO 150
#define KT 9
#define MM 7500          // T*V rows per n
#define MT 59            // ceil(7500/128)

typedef short s8v  __attribute__((ext_vector_type(8)));
typedef float f4v  __attribute__((ext_vector_type(4)));

__device__ __forceinline__ float b2f(u16 u){
  union { u32 i; float f; } c; c.i = ((u32)u) << 16; return c.f;
}
__device__ __forceinline__ u16 f2b(float f){
  __hip_bfloat16 h = __float2bfloat16(f);
  return *reinterpret_cast<u16*>(&h);
}
__device__ __forceinline__ void async16(const void* g, void* l){
  __builtin_amdgcn_global_load_lds((const __attribute__((address_space(1))) u32*)g,
                                   (__attribute__((address_space(3))) u32*)l, 16, 0, 0);
}

// ---------------- prep: A_sum + zero-page + tcn_w repack + gcn_w bf16 ----------------
__global__ __launch_bounds__(256) void k_prep(const float* __restrict__ Ap, const float* __restrict__ ei,
                                              const float* __restrict__ tw, const float* __restrict__ gw,
                                              float* __restrict__ Asum, float* __restrict__ zbuf,
                                              u16* __restrict__ Wq2, u16* __restrict__ gwb){
  int idx = blockIdx.x * 256 + threadIdx.x;
  if (idx < VV*VV){
    float s = 0.f;
    for (int p = 0; p < 3; ++p) s += ei[p] * Ap[p*VV*VV + idx];
    Asum[idx] = s;
  }
  if (idx >= 640 && idx < 768) zbuf[idx - 640] = 0.f;   // 512 B zero page
  int w = idx - 1024;
  if (w >= 0 && w < 18*OO*64){
    int kc = w >> 13;
    int r  = w & 8191;
    int o  = r >> 6;
    int j  = r & 63;
    int k  = kc >> 1;
    int i  = (kc & 1)*64 + j;
    Wq2[w] = f2b(tw[o*(OO*KT) + i*KT + k]);   // Wq2[kc][o][j] = tcn_w[o][i][k]
  }
  int w2 = idx - 148480;
  if (w2 >= 0 && w2 < OO*CC) gwb[w2] = f2b(gw[w2]);   // gwb[o][c]
}

// ---------------- gcn as MFMA implicit GEMM: M=(t*25+v), N=128 o, K=64 c ----------------
// xg layout: [n][m=t*25+v][o].  No async16, LDS < 64 KB.
__global__ __launch_bounds__(256) void k_gcnm(const float* __restrict__ x, const float* __restrict__ Asum,
                                              const u16* __restrict__ gwb, const float* __restrict__ gb,
                                              u16* __restrict__ xg){
  __shared__ __align__(16) u16  xs[CC*177];     // 22656 B: x[n][c][t0..t0+6][v] bf16, odd stride
  __shared__ __align__(16) float As2[VV*26];    // 2600 B
  __shared__ __align__(16) u16 A_lds[128*64];   // 16 KB, XOR-swizzled granules
  __shared__ __align__(16) u16 B_lds[128*64];   // 16 KB, XOR-swizzled granules
  int bx = blockIdx.x;
  int n  = bx / MT;
  int m0 = (bx % MT) * 128;
  int t0 = m0 / VV;
  int tid = threadIdx.x;
  int lane = tid & 63, wv = tid >> 6;
  int wm = (wv & 1) * 64, wo = (wv >> 1) * 64;
  int lr = lane & 15, lq = lane >> 4;

  // ---- stage B (gwb, 16 KB) with plain coalesced loads + swizzled ds_write ----
  {
    const u32* g32 = (const u32*)gwb;
    u32* b32 = (u32*)B_lds;
    for (int s = tid; s < 4096; s += 256){
      int row = s >> 5, col = s & 31;          // 32 u32 per 64-elem row
      int g = col >> 2, c2 = col & 3;
      b32[row*32 + ((g ^ (row & 7))*4 + c2)] = g32[s];
    }
  }

  // ---- stage x slice: 64c x 7t x 25v as bf16 (zero-fill t>=300) ----
  #pragma unroll
  for (int it = 0; it < 7; ++it){
    int t = t0 + it;
    bool ok = (t < TT);
    for (int s = tid; s < CC*VV; s += 256){
      int c = s / VV, v = s - c*VV;
      xs[c*177 + it*VV + v] = ok ? f2b(x[((size_t)(n*CC + c)*TT + t)*VV + v]) : (u16)0;
    }
  }
  for (int s = tid; s < VV*VV; s += 256){
    int v = s / VV, w = s - v*VV;
    As2[v*26 + w] = Asum[s];
  }
  __syncthreads();

  // ---- compute agg tile into A_lds (bf16, swizzled): task (m,g): 8 c, 25 v ----
  #pragma unroll
  for (int qq = 0; qq < 4; ++qq){
    int q = qq*256 + tid;
    int m = q >> 3, g = q & 7;
    int mg = m0 + m;
    int t  = mg / VV, w = mg - t*VV;
    int it = t - t0;
    u16 pk[8];
    #pragma unroll
    for (int cc = 0; cc < 8; ++cc){
      int c = g*8 + cc;
      float acc = 0.f;
      #pragma unroll
      for (int v = 0; v < VV; ++v) acc += b2f(xs[c*177 + it*VV + v]) * As2[v*26 + w];
      pk[cc] = f2b(acc);
    }
    *(s8v*)&A_lds[m*64 + ((g ^ (m & 7)) * 8)] = *(s8v*)pk;
  }
  __syncthreads();

  // ---- 32 MFMA: quadrant 64m x 64o per wave, K=64 (2 substeps) ----
  f4v acc[4][4];
  #pragma unroll
  for (int mi = 0; mi < 4; ++mi)
    #pragma unroll
    for (int ni = 0; ni < 4; ++ni) acc[mi][ni] = (f4v)(0.f);
  #pragma unroll
  for (int ks = 0; ks < 2; ++ks){
    int p = ((ks*4 + lq) ^ (lane & 7)) * 8;
    s8v af[4], bf[4];
    #pragma unroll
    for (int mi = 0; mi < 4; ++mi)
      af[mi] = *(const s8v*)&A_lds[(wm + mi*16 + lr)*64 + p];
    #pragma unroll
    for (int ni = 0; ni < 4; ++ni)
      bf[ni] = *(const s8v*)&B_lds[(wo + ni*16 + lr)*64 + p];
    #pragma unroll
    for (int mi = 0; mi < 4; ++mi)
      #pragma unroll
      for (int ni = 0; ni < 4; ++ni)
        acc[mi][ni] = __builtin_amdgcn_mfma_f32_16x16x32_bf16(af[mi], bf[ni], acc[mi][ni], 0, 0, 0);
  }

  // ---- epilogue ----
  float bias[4];
  #pragma unroll
  for (int ni = 0; ni < 4; ++ni) bias[ni] = gb[wo + ni*16 + lr];
  #pragma unroll
  for (int mi = 0; mi < 4; ++mi){
    int mr = m0 + wm + mi*16 + lq*4;
    #pragma unroll
    for (int ni = 0; ni < 4; ++ni){
      int o = wo + ni*16 + lr;
      #pragma unroll
      for (int rg = 0; rg < 4; ++rg){
        int m = mr + rg;
        if (m < MM)
          xg[((size_t)n*MM + m)*OO + o] = f2b(acc[mi][ni][rg] + bias[ni]);
      }
    }
  }
}

// ---------------- tcn as MFMA implicit GEMM: M=(v*150+t2) per n, N=128 o, K=1152 ----------------
// xt layout: [n][m=v*150+t2][o]
__global__ __launch_bounds__(256) void k_tcnm(const u16* __restrict__ xg, const u16* __restrict__ Wq2,
                                              const float* __restrict__ tb, const u16* __restrict__ zbuf,
                                              u16* __restrict__ xt){
  __shared__ __align__(16) u16 A_lds[128*64];
  __shared__ __align__(16) u16 B_lds[128*64];
  int bx = blockIdx.x;
  int n  = bx / 30;
  int m0 = (bx % 30) * 128;
  int tid = threadIdx.x;
  int lane = tid & 63, wv = tid >> 6;
  int wm = (wv & 1) * 64, wo = (wv >> 1) * 64;
  int lr = lane & 15, lq = lane >> 4;

  int rlow = tid >> 3;
  int gsrc = (tid & 7) ^ (rlow & 7);
  int tid16 = tid * 16;
  int  tbase[4]; size_t c0[4]; bool vm[4];
  #pragma unroll
  for (int it = 0; it < 4; ++it){
    int m = m0 + it*32 + rlow;
    vm[it] = (m < 3750);
    int v  = m / TO, t2 = m % TO;
    tbase[it] = 2*t2 - 4;
    c0[it] = (size_t)n*(TT*VV*OO) + (size_t)v*OO + gsrc*8;
  }

  f4v acc[4][4];
  #pragma unroll
  for (int mi = 0; mi < 4; ++mi)
    #pragma unroll
    for (int ni = 0; ni < 4; ++ni) acc[mi][ni] = (f4v)(0.f);

  for (int kc = 0; kc < 18; ++kc){
    int k  = kc >> 1;
    int i0 = (kc & 1) * 64;
    const u16* wbase = Wq2 + kc*8192;
    #pragma unroll
    for (int it = 0; it < 4; ++it){
      int t = tbase[it] + k;
      const u16* ga = (vm[it] && t >= 0 && t < TT)
                      ? xg + c0[it] + (size_t)t*(VV*OO) + i0
                      : zbuf;
      async16(ga, (char*)A_lds + it*4096 + tid16);
      async16(wbase + ((it*32 + rlow)*64 + gsrc*8), (char*)B_lds + it*4096 + tid16);
    }
    __syncthreads();
    #pragma unroll
    for (int ks = 0; ks < 2; ++ks){
      int p = ((ks*4 + lq) ^ (lane & 7)) * 8;
      s8v af[4], bf[4];
      #pragma unroll
      for (int mi = 0; mi < 4; ++mi)
        af[mi] = *(const s8v*)&A_lds[(wm + mi*16 + lr)*64 + p];
      #pragma unroll
      for (int ni = 0; ni < 4; ++ni)
        bf[ni] = *(const s8v*)&B_lds[(wo + ni*16 + lr)*64 + p];
      #pragma unroll
      for (int mi = 0; mi < 4; ++mi)
        #pragma unroll
        for (int ni = 0; ni < 4; ++ni)
          acc[mi][ni] = __builtin_amdgcn_mfma_f32_16x16x32_bf16(af[mi], bf[ni], acc[mi][ni], 0, 0, 0);
    }
    __syncthreads();
  }

  float bias[4];
  #pragma unroll
  for (int ni = 0; ni < 4; ++ni) bias[ni] = tb[wo + ni*16 + lr];
  #pragma unroll
  for (int mi = 0; mi < 4; ++mi){
    int mr = m0 + wm + mi*16 + lq*4;
    #pragma unroll
    for (int ni = 0; ni < 4; ++ni){
      int o = wo + ni*16 + lr;
      #pragma unroll
      for (int rg = 0; rg < 4; ++rg){
        int m = mr + rg;
        if (m < 3750)
          xt[((size_t)n*3750 + m)*OO + o] = f2b(acc[mi][ni][rg] + bias[ni]);
      }
    }
  }
}

// ---------------- BN stats ----------------
__global__ __launch_bounds__(256) void k_stats1(const u16* __restrict__ xt, float* __restrict__ psum,
                                                float* __restrict__ psq){
  __shared__ float ls[256], lq[256];
  int tid = threadIdx.x;
  int o = tid & 127, rh = tid >> 7;
  int r0 = blockIdx.x * 480;
  float s = 0.f, q = 0.f;
  for (int r = r0 + rh; r < r0 + 480; r += 2){
    float f = b2f(xt[(size_t)r*OO + o]);
    s += f; q += f*f;
  }
  ls[tid] = s; lq[tid] = q;
  __syncthreads();
  if (tid < 128){
    psum[blockIdx.x*128 + o] = ls[tid] + ls[tid + 128];
    psq [blockIdx.x*128 + o] = lq[tid] + lq[tid + 128];
  }
}

__global__ __launch_bounds__(128) void k_stats2(const float* __restrict__ psum, const float* __restrict__ psq,
                                                const float* __restrict__ gamma, const float* __restrict__ beta,
                                                float* __restrict__ stats){
  int o = threadIdx.x;
  float s = 0.f, q = 0.f;
  for (int b = 0; b < 250; ++b){ s += psum[b*128 + o]; q += psq[b*128 + o]; }
  const float inv = 1.f / 120000.f;
  float mean = s * inv;
  float var  = q * inv - mean*mean;
  float sc = gamma[o] * rsqrtf(var + 1e-5f);
  stats[o]       = sc;
  stats[128 + o] = beta[o] - mean * sc;
}

// ---------------- final: res GEMM (K=64) + BN affine + relu; LDS-staged writes ----------------
__global__ __launch_bounds__(256) void k_final(const float* __restrict__ x, const u16* __restrict__ xt,
                                               const float* __restrict__ stats, const float* __restrict__ rw,
                                               const float* __restrict__ rb, float* __restrict__ out){
  __shared__ __align__(16) float xs[VV][72];
  __shared__ __align__(16) float og[OO*VV];
  int n = blockIdx.x / TO, t2 = blockIdx.x % TO;
  int tid = threadIdx.x;
  const float* xb = x + (size_t)n*CC*TT*VV + (size_t)(2*t2)*VV;
  for (int idx = tid; idx < CC*VV; idx += 256){
    int c = idx / VV, v = idx - c*VV;
    xs[v][c] = xb[(size_t)c*(TT*VV) + v];
  }
  __syncthreads();
  int vq = tid & 7, ot = tid >> 3;
  int nv = (vq == 0) ? 4 : 3;
  float acc[4][4];
  #pragma unroll
  for (int q = 0; q < 4; ++q)
    #pragma unroll
    for (int j = 0; j < 4; ++j) acc[q][j] = 0.f;
  for (int c4 = 0; c4 < CC; c4 += 4){
    float4 a[4];
    for (int j = 0; j < nv; ++j) a[j] = *(const float4*)&xs[vq + 8*j][c4];
    #pragma unroll
    for (int q = 0; q < 4; ++q){
      int o = ot + q*32;
      float4 g = *(const float4*)&rw[o*CC + c4];
      for (int j = 0; j < nv; ++j)
        acc[q][j] += a[j].x*g.x + a[j].y*g.y + a[j].z*g.z + a[j].w*g.w;
    }
  }
  #pragma unroll
  for (int q = 0; q < 4; ++q){
    int o = ot + q*32;
    float sc = stats[o], sb = stats[128 + o], rbo = rb[o];
    for (int j = 0; j < nv; ++j){
      int v = vq + 8*j;
      float xtv = b2f(xt[((size_t)n*3750 + (size_t)v*TO + t2)*OO + o]);
      float r = sc*xtv + sb + acc[q][j] + rbo;
      og[o*VV + v] = fmaxf(r, 0.f);
    }
  }
  __syncthreads();
  for (int idx = tid; idx < OO*VV; idx += 256){
    int o = idx / VV, v = idx - o*VV;
    out[((size_t)(n*OO + o)*TO + t2)*VV + v] = og[idx];
  }
}

extern "C" void kernel_launch(void* const* d_in, const int* in_sizes, int n_in,
                              void* d_out, int out_size, void* d_ws, size_t ws_size,
                              hipStream_t stream) {
  const float* x     = (const float*)d_in[0];
  const float* Ap    = (const float*)d_in[1];
  const float* ei    = (const float*)d_in[2];
  const float* gw    = (const float*)d_in[3];
  const float* gb    = (const float*)d_in[4];
  const float* tw    = (const float*)d_in[5];
  const float* tb    = (const float*)d_in[6];
  const float* gamma = (const float*)d_in[7];
  const float* beta  = (const float*)d_in[8];
  const float* rw    = (const float*)d_in[9];
  const float* rb    = (const float*)d_in[10];
  float* out = (float*)d_out;

  char* ws = (char*)d_ws;
  float* Asum  = (float*)ws;                      // 2500 B
  float* zbuf  = (float*)(ws + 2560);             // 512 B zero page
  u16*   Wq2   = (u16*)(ws + 4096);               // 294912 B
  float* psum  = (float*)(ws + 299008);           // 128000 B
  float* psq   = (float*)(ws + 427008);           // 128000 B
  float* stats = (float*)(ws + 555008);           // 1024 B
  u16*   gwb   = (u16*)(ws + 556032);             // 16384 B
  u16*   xg    = (u16*)(ws + (1u<<20));           // 61,440,000 B [n][m=t*25+v][o] bf16
  u16*   xt    = (u16*)(ws + 62488576);           // 28,800,000 B [n][m=v*150+t2][o] bf16

  k_prep  <<<dim3(612),    dim3(256), 0, stream>>>(Ap, ei, tw, gw, Asum, zbuf, Wq2, gwb);
  k_gcnm  <<<dim3(NB*MT),  dim3(256), 0, stream>>>(x, Asum, gwb, gb, xg);
  k_tcnm  <<<dim3(NB*30),  dim3(256), 0, stream>>>(xg, Wq2, tb, (const u16*)zbuf, xt);
  k_stats1<<<dim3(250),    dim3(256), 0, stream>>>(xt, psum, psq);
  k_stats2<<<dim3(1),      dim3(128), 0, stream>>>(psum, psq, gamma, beta, stats);
  k_final <<<dim3(NB*TO),  dim3(256), 0, stream>>>(x, xt, stats, rw, rb, out);
}

// Round 7
// 499.999 us; speedup vs baseline: 5.1963x; 2.3886x over previous
//
#include <hip/hip_runtime.h>
#include <hip/hip_bf16.h>

typedef unsigned short u16;
typedef unsigned int   u32;

#define NB 32
#define CC 64
#define TT 300
#define VV 25
#define OO 128
#define TO 150
#define KT 9
#define MM 7500          // T*V rows per n (gcn GEMM)
#define MT 59            // ceil(7500/128)
#define M2 3750          // T2*V rows per n (tcn/res GEMMs)

typedef short s8v  __attribute__((ext_vector_type(8)));
typedef float f4v  __attribute__((ext_vector_type(4)));

__device__ __forceinline__ float b2f(u16 u){
  union { u32 i; float f; } c; c.i = ((u32)u) << 16; return c.f;
}
__device__ __forceinline__ u16 f2b(float f){
  __hip_bfloat16 h = __float2bfloat16(f);
  return *reinterpret_cast<u16*>(&h);
}
__device__ __forceinline__ void async16(const void* g, void* l){
  __builtin_amdgcn_global_load_lds((const __attribute__((address_space(1))) u32*)g,
                                   (__attribute__((address_space(3))) u32*)l, 16, 0, 0);
}

// ---------------- prep: A_sum + zero-page + tcn_w repack + gcn_w/res_w bf16 ----------------
__global__ __launch_bounds__(256) void k_prep(const float* __restrict__ Ap, const float* __restrict__ ei,
                                              const float* __restrict__ tw, const float* __restrict__ gw,
                                              const float* __restrict__ rw,
                                              float* __restrict__ Asum, float* __restrict__ zbuf,
                                              u16* __restrict__ Wq2, u16* __restrict__ gwb,
                                              u16* __restrict__ rwb){
  int idx = blockIdx.x * 256 + threadIdx.x;
  if (idx < VV*VV){
    float s = 0.f;
    for (int p = 0; p < 3; ++p) s += ei[p] * Ap[p*VV*VV + idx];
    Asum[idx] = s;
  }
  if (idx >= 640 && idx < 768) zbuf[idx - 640] = 0.f;   // 512 B zero page
  int w = idx - 1024;
  if (w >= 0 && w < 18*OO*64){
    int kc = w >> 13;
    int r  = w & 8191;
    int o  = r >> 6;
    int j  = r & 63;
    int k  = kc >> 1;
    int i  = (kc & 1)*64 + j;
    Wq2[w] = f2b(tw[o*(OO*KT) + i*KT + k]);   // Wq2[kc][o][j] = tcn_w[o][i][k]
  }
  int w2 = idx - 148480;
  if (w2 >= 0 && w2 < OO*CC) gwb[w2] = f2b(gw[w2]);   // gwb[o][c]
  int w3 = idx - 156672;
  if (w3 >= 0 && w3 < OO*CC) rwb[w3] = f2b(rw[w3]);   // rwb[o][c]
}

// ---------------- gcn as MFMA implicit GEMM: M=(t*25+v), N=128 o, K=64 c ----------------
// xg layout: [n][m=t*25+v][o].  No async16, LDS < 64 KB.
__global__ __launch_bounds__(256) void k_gcnm(const float* __restrict__ x, const float* __restrict__ Asum,
                                              const u16* __restrict__ gwb, const float* __restrict__ gb,
                                              u16* __restrict__ xg){
  __shared__ __align__(16) u16  xs[CC*177];     // 22656 B: x[n][c][t0..t0+6][v] bf16
  __shared__ __align__(16) float As2[VV*26];    // 2600 B
  __shared__ __align__(16) u16 A_lds[128*64];   // 16 KB, XOR-swizzled granules
  __shared__ __align__(16) u16 B_lds[128*64];   // 16 KB, XOR-swizzled granules
  int bx = blockIdx.x;
  int n  = bx / MT;
  int m0 = (bx % MT) * 128;
  int t0 = m0 / VV;
  int tid = threadIdx.x;
  int lane = tid & 63, wv = tid >> 6;
  int wm = (wv & 1) * 64, wo = (wv >> 1) * 64;
  int lr = lane & 15, lq = lane >> 4;

  {
    const u32* g32 = (const u32*)gwb;
    u32* b32 = (u32*)B_lds;
    for (int s = tid; s < 4096; s += 256){
      int row = s >> 5, col = s & 31;
      int g = col >> 2, c2 = col & 3;
      b32[row*32 + ((g ^ (row & 7))*4 + c2)] = g32[s];
    }
  }

  #pragma unroll
  for (int it = 0; it < 7; ++it){
    int t = t0 + it;
    bool ok = (t < TT);
    for (int s = tid; s < CC*VV; s += 256){
      int c = s / VV, v = s - c*VV;
      xs[c*177 + it*VV + v] = ok ? f2b(x[((size_t)(n*CC + c)*TT + t)*VV + v]) : (u16)0;
    }
  }
  for (int s = tid; s < VV*VV; s += 256){
    int v = s / VV, w = s - v*VV;
    As2[v*26 + w] = Asum[s];
  }
  __syncthreads();

  #pragma unroll
  for (int qq = 0; qq < 4; ++qq){
    int q = qq*256 + tid;
    int m = q >> 3, g = q & 7;
    int mg = m0 + m;
    int t  = mg / VV, w = mg - t*VV;
    int it = t - t0;
    u16 pk[8];
    #pragma unroll
    for (int cc = 0; cc < 8; ++cc){
      int c = g*8 + cc;
      float acc = 0.f;
      #pragma unroll
      for (int v = 0; v < VV; ++v) acc += b2f(xs[c*177 + it*VV + v]) * As2[v*26 + w];
      pk[cc] = f2b(acc);
    }
    *(s8v*)&A_lds[m*64 + ((g ^ (m & 7)) * 8)] = *(s8v*)pk;
  }
  __syncthreads();

  f4v acc[4][4];
  #pragma unroll
  for (int mi = 0; mi < 4; ++mi)
    #pragma unroll
    for (int ni = 0; ni < 4; ++ni) acc[mi][ni] = (f4v)(0.f);
  #pragma unroll
  for (int ks = 0; ks < 2; ++ks){
    int p = ((ks*4 + lq) ^ (lane & 7)) * 8;
    s8v af[4], bf[4];
    #pragma unroll
    for (int mi = 0; mi < 4; ++mi)
      af[mi] = *(const s8v*)&A_lds[(wm + mi*16 + lr)*64 + p];
    #pragma unroll
    for (int ni = 0; ni < 4; ++ni)
      bf[ni] = *(const s8v*)&B_lds[(wo + ni*16 + lr)*64 + p];
    #pragma unroll
    for (int mi = 0; mi < 4; ++mi)
      #pragma unroll
      for (int ni = 0; ni < 4; ++ni)
        acc[mi][ni] = __builtin_amdgcn_mfma_f32_16x16x32_bf16(af[mi], bf[ni], acc[mi][ni], 0, 0, 0);
  }

  float bias[4];
  #pragma unroll
  for (int ni = 0; ni < 4; ++ni) bias[ni] = gb[wo + ni*16 + lr];
  #pragma unroll
  for (int mi = 0; mi < 4; ++mi){
    int mr = m0 + wm + mi*16 + lq*4;
    #pragma unroll
    for (int ni = 0; ni < 4; ++ni){
      int o = wo + ni*16 + lr;
      #pragma unroll
      for (int rg = 0; rg < 4; ++rg){
        int m = mr + rg;
        if (m < MM)
          xg[((size_t)n*MM + m)*OO + o] = f2b(acc[mi][ni][rg] + bias[ni]);
      }
    }
  }
}

// ---------------- tcn as MFMA implicit GEMM: M=(t2*25+v), N=128 o, K=1152 ----------------
// xt layout: [n][m=t2*25+v][o]
__global__ __launch_bounds__(256) void k_tcnm(const u16* __restrict__ xg, const u16* __restrict__ Wq2,
                                              const float* __restrict__ tb, const u16* __restrict__ zbuf,
                                              u16* __restrict__ xt){
  __shared__ __align__(16) u16 A_lds[128*64];
  __shared__ __align__(16) u16 B_lds[128*64];
  int bx = blockIdx.x;
  int n  = bx / 30;
  int m0 = (bx % 30) * 128;
  int tid = threadIdx.x;
  int lane = tid & 63, wv = tid >> 6;
  int wm = (wv & 1) * 64, wo = (wv >> 1) * 64;
  int lr = lane & 15, lq = lane >> 4;

  int rlow = tid >> 3;
  int gsrc = (tid & 7) ^ (rlow & 7);
  int tid16 = tid * 16;
  int  tbse[4], vr[4]; bool vm[4];
  #pragma unroll
  for (int it = 0; it < 4; ++it){
    int m = m0 + it*32 + rlow;
    vm[it] = (m < M2);
    int t2 = m / VV, v = m - t2*VV;
    tbse[it] = 2*t2 - 4;
    vr[it] = v;
  }
  size_t basen = (size_t)n*MM*OO + (size_t)gsrc*8;

  f4v acc[4][4];
  #pragma unroll
  for (int mi = 0; mi < 4; ++mi)
    #pragma unroll
    for (int ni = 0; ni < 4; ++ni) acc[mi][ni] = (f4v)(0.f);

  for (int kc = 0; kc < 18; ++kc){
    int k  = kc >> 1;
    int i0 = (kc & 1) * 64;
    const u16* wbase = Wq2 + kc*8192;
    #pragma unroll
    for (int it = 0; it < 4; ++it){
      int t = tbse[it] + k;
      const u16* ga = (vm[it] && t >= 0 && t < TT)
                      ? xg + basen + (size_t)(t*VV + vr[it])*OO + i0
                      : zbuf;
      async16(ga, (char*)A_lds + it*4096 + tid16);
      async16(wbase + ((it*32 + rlow)*64 + gsrc*8), (char*)B_lds + it*4096 + tid16);
    }
    __syncthreads();
    #pragma unroll
    for (int ks = 0; ks < 2; ++ks){
      int p = ((ks*4 + lq) ^ (lane & 7)) * 8;
      s8v af[4], bf[4];
      #pragma unroll
      for (int mi = 0; mi < 4; ++mi)
        af[mi] = *(const s8v*)&A_lds[(wm + mi*16 + lr)*64 + p];
      #pragma unroll
      for (int ni = 0; ni < 4; ++ni)
        bf[ni] = *(const s8v*)&B_lds[(wo + ni*16 + lr)*64 + p];
      #pragma unroll
      for (int mi = 0; mi < 4; ++mi)
        #pragma unroll
        for (int ni = 0; ni < 4; ++ni)
          acc[mi][ni] = __builtin_amdgcn_mfma_f32_16x16x32_bf16(af[mi], bf[ni], acc[mi][ni], 0, 0, 0);
    }
    __syncthreads();
  }

  float bias[4];
  #pragma unroll
  for (int ni = 0; ni < 4; ++ni) bias[ni] = tb[wo + ni*16 + lr];
  #pragma unroll
  for (int mi = 0; mi < 4; ++mi){
    int mr = m0 + wm + mi*16 + lq*4;
    #pragma unroll
    for (int ni = 0; ni < 4; ++ni){
      int o = wo + ni*16 + lr;
      #pragma unroll
      for (int rg = 0; rg < 4; ++rg){
        int m = mr + rg;
        if (m < M2)
          xt[((size_t)n*M2 + m)*OO + o] = f2b(acc[mi][ni][rg] + bias[ni]);
      }
    }
  }
}

// ---------------- BN stats ----------------
__global__ __launch_bounds__(256) void k_stats1(const u16* __restrict__ xt, float* __restrict__ psum,
                                                float* __restrict__ psq){
  __shared__ float ls[256], lq[256];
  int tid = threadIdx.x;
  int o = tid & 127, rh = tid >> 7;
  int r0 = blockIdx.x * 480;
  float s = 0.f, q = 0.f;
  for (int r = r0 + rh; r < r0 + 480; r += 2){
    float f = b2f(xt[(size_t)r*OO + o]);
    s += f; q += f*f;
  }
  ls[tid] = s; lq[tid] = q;
  __syncthreads();
  if (tid < 128){
    psum[blockIdx.x*128 + o] = ls[tid] + ls[tid + 128];
    psq [blockIdx.x*128 + o] = lq[tid] + lq[tid + 128];
  }
}

__global__ __launch_bounds__(128) void k_stats2(const float* __restrict__ psum, const float* __restrict__ psq,
                                                const float* __restrict__ gamma, const float* __restrict__ beta,
                                                float* __restrict__ stats){
  int o = threadIdx.x;
  float s = 0.f, q = 0.f;
  for (int b = 0; b < 250; ++b){ s += psum[b*128 + o]; q += psq[b*128 + o]; }
  const float inv = 1.f / 120000.f;
  float mean = s * inv;
  float var  = q * inv - mean*mean;
  float sc = gamma[o] * rsqrtf(var + 1e-5f);
  stats[o]       = sc;
  stats[128 + o] = beta[o] - mean * sc;
}

// ---------------- res as MFMA implicit GEMM + BN + relu: M=(t2*25+v), N=128 o, K=64 c ----------------
// out[n][o][m] with m = t2*25+v  (== reference (N,O,T2,V))
__global__ __launch_bounds__(256) void k_resm(const float* __restrict__ x, const u16* __restrict__ rwb,
                                              const float* __restrict__ rb, const u16* __restrict__ xt,
                                              const float* __restrict__ stats, float* __restrict__ out){
  __shared__ __align__(16) u16 A_lds[128*64];   // 16 KB
  __shared__ __align__(16) u16 B_lds[128*64];   // 16 KB
  int bx = blockIdx.x;
  int n  = bx / 30;
  int m0 = (bx % 30) * 128;
  int t20 = m0 / VV, r0 = m0 % VV;
  int tid = threadIdx.x;
  int lane = tid & 63, wv = tid >> 6;
  int wm = (wv & 1) * 64, wo = (wv >> 1) * 64;
  int lr = lane & 15, lq = lane >> 4;

  // stage B (rwb) with swizzled ds_write
  {
    const u32* g32 = (const u32*)rwb;
    u32* b32 = (u32*)B_lds;
    for (int s = tid; s < 4096; s += 256){
      int row = s >> 5, col = s & 31;
      int g = col >> 2, c2 = col & 3;
      b32[row*32 + ((g ^ (row & 7))*4 + c2)] = g32[s];
    }
  }

  // stage A: x_sub[n][c][t2][v] -> A_lds[m=t2*25+v - m0][c] bf16 swizzled
  for (int idx = tid; idx < 7*CC*VV; idx += 256){
    int t2i = idx / (CC*VV);
    int rem = idx - t2i*(CC*VV);
    int c = rem / VV, v = rem - c*VV;
    int t2 = t20 + t2i;
    int ml = t2i*VV + v - r0;
    if (ml >= 0 && ml < 128){
      float val = (t2 < TO) ? x[((size_t)(n*CC + c)*TT + 2*t2)*VV + v] : 0.f;
      A_lds[ml*64 + (((c >> 3) ^ (ml & 7))*8 + (c & 7))] = f2b(val);
    }
  }
  __syncthreads();

  f4v acc[4][4];
  #pragma unroll
  for (int mi = 0; mi < 4; ++mi)
    #pragma unroll
    for (int ni = 0; ni < 4; ++ni) acc[mi][ni] = (f4v)(0.f);
  #pragma unroll
  for (int ks = 0; ks < 2; ++ks){
    int p = ((ks*4 + lq) ^ (lane & 7)) * 8;
    s8v af[4], bf[4];
    #pragma unroll
    for (int mi = 0; mi < 4; ++mi)
      af[mi] = *(const s8v*)&A_lds[(wm + mi*16 + lr)*64 + p];
    #pragma unroll
    for (int ni = 0; ni < 4; ++ni)
      bf[ni] = *(const s8v*)&B_lds[(wo + ni*16 + lr)*64 + p];
    #pragma unroll
    for (int mi = 0; mi < 4; ++mi)
      #pragma unroll
      for (int ni = 0; ni < 4; ++ni)
        acc[mi][ni] = __builtin_amdgcn_mfma_f32_16x16x32_bf16(af[mi], bf[ni], acc[mi][ni], 0, 0, 0);
  }

  // epilogue: BN(xt) + res + relu, direct m-contiguous stores
  float sc[4], sb[4], rr[4];
  #pragma unroll
  for (int ni = 0; ni < 4; ++ni){
    int o = wo + ni*16 + lr;
    sc[ni] = stats[o]; sb[ni] = stats[128 + o]; rr[ni] = rb[o];
  }
  #pragma unroll
  for (int mi = 0; mi < 4; ++mi){
    int mb = m0 + wm + mi*16 + lq*4;
    #pragma unroll
    for (int ni = 0; ni < 4; ++ni){
      int o = wo + ni*16 + lr;
      size_t xb = ((size_t)n*M2 + mb)*OO + o;
      size_t ob = ((size_t)(n*OO + o))*M2 + mb;
      if (mb + 3 < M2){
        float r0_ = fmaxf(sc[ni]*b2f(xt[xb])        + sb[ni] + acc[mi][ni][0] + rr[ni], 0.f);
        float r1_ = fmaxf(sc[ni]*b2f(xt[xb + OO])   + sb[ni] + acc[mi][ni][1] + rr[ni], 0.f);
        float r2_ = fmaxf(sc[ni]*b2f(xt[xb + 2*OO]) + sb[ni] + acc[mi][ni][2] + rr[ni], 0.f);
        float r3_ = fmaxf(sc[ni]*b2f(xt[xb + 3*OO]) + sb[ni] + acc[mi][ni][3] + rr[ni], 0.f);
        *(float2*)&out[ob]     = make_float2(r0_, r1_);
        *(float2*)&out[ob + 2] = make_float2(r2_, r3_);
      } else {
        #pragma unroll
        for (int rg = 0; rg < 4; ++rg){
          int m = mb + rg;
          if (m < M2){
            float r = sc[ni]*b2f(xt[xb + (size_t)rg*OO]) + sb[ni] + acc[mi][ni][rg] + rr[ni];
            out[ob + rg] = fmaxf(r, 0.f);
          }
        }
      }
    }
  }
}

extern "C" void kernel_launch(void* const* d_in, const int* in_sizes, int n_in,
                              void* d_out, int out_size, void* d_ws, size_t ws_size,
                              hipStream_t stream) {
  const float* x     = (const float*)d_in[0];
  const float* Ap    = (const float*)d_in[1];
  const float* ei    = (const float*)d_in[2];
  const float* gw    = (const float*)d_in[3];
  const float* gb    = (const float*)d_in[4];
  const float* tw    = (const float*)d_in[5];
  const float* tb    = (const float*)d_in[6];
  const float* gamma = (const float*)d_in[7];
  const float* beta  = (const float*)d_in[8];
  const float* rw    = (const float*)d_in[9];
  const float* rb    = (const float*)d_in[10];
  float* out = (float*)d_out;

  char* ws = (char*)d_ws;
  float* Asum  = (float*)ws;                      // 2500 B
  float* zbuf  = (float*)(ws + 2560);             // 512 B zero page
  u16*   Wq2   = (u16*)(ws + 4096);               // 294912 B
  float* psum  = (float*)(ws + 299008);           // 128000 B
  float* psq   = (float*)(ws + 427008);           // 128000 B
  float* stats = (float*)(ws + 555008);           // 1024 B
  u16*   gwb   = (u16*)(ws + 556032);             // 16384 B
  u16*   rwb   = (u16*)(ws + 572416);             // 16384 B
  u16*   xg    = (u16*)(ws + (1u<<20));           // 61,440,000 B [n][m=t*25+v][o] bf16
  u16*   xt    = (u16*)(ws + 62488576);           // 28,800,000 B [n][m=t2*25+v][o] bf16

  k_prep  <<<dim3(644),    dim3(256), 0, stream>>>(Ap, ei, tw, gw, rw, Asum, zbuf, Wq2, gwb, rwb);
  k_gcnm  <<<dim3(NB*MT),  dim3(256), 0, stream>>>(x, Asum, gwb, gb, xg);
  k_tcnm  <<<dim3(NB*30),  dim3(256), 0, stream>>>(xg, Wq2, tb, (const u16*)zbuf, xt);
  k_stats1<<<dim3(250),    dim3(256), 0, stream>>>(xt, psum, psq);
  k_stats2<<<dim3(1),      dim3(128), 0, stream>>>(psum, psq, gamma, beta, stats);
  k_resm  <<<dim3(NB*30),  dim3(256), 0, stream>>>(x, rwb, rb, xt, stats, out);
}

// Round 8
// 464.956 us; speedup vs baseline: 5.5879x; 1.0754x over previous
//
#include <hip/hip_runtime.h>
#include <hip/hip_bf16.h>

typedef unsigned short u16;
typedef unsigned int   u32;

#define NB 32
#define CC 64
#define TT 300
#define VV 25
#define OO 128
#define TO 150
#define KT 9
#define MM 7500          // T*V rows per n (gcn GEMM)
#define MT 59            // ceil(7500/128)
#define M2 3750          // T2*V rows per n (tcn/res GEMMs)

typedef short s8v  __attribute__((ext_vector_type(8)));
typedef float f4v  __attribute__((ext_vector_type(4)));
typedef u16  h4v  __attribute__((ext_vector_type(4)));

__device__ __forceinline__ float b2f(u16 u){
  union { u32 i; float f; } c; c.i = ((u32)u) << 16; return c.f;
}
__device__ __forceinline__ u16 f2b(float f){
  __hip_bfloat16 h = __float2bfloat16(f);
  return *reinterpret_cast<u16*>(&h);
}
__device__ __forceinline__ void async16(const void* g, void* l){
  __builtin_amdgcn_global_load_lds((const __attribute__((address_space(1))) u32*)g,
                                   (__attribute__((address_space(3))) u32*)l, 16, 0, 0);
}

// ---------------- prep: A_sum + zero-page + tcn_w repack + gcn_w/res_w bf16 ----------------
__global__ __launch_bounds__(256) void k_prep(const float* __restrict__ Ap, const float* __restrict__ ei,
                                              const float* __restrict__ tw, const float* __restrict__ gw,
                                              const float* __restrict__ rw,
                                              float* __restrict__ Asum, float* __restrict__ zbuf,
                                              u16* __restrict__ Wq2, u16* __restrict__ gwb,
                                              u16* __restrict__ rwb){
  int idx = blockIdx.x * 256 + threadIdx.x;
  if (idx < VV*VV){
    float s = 0.f;
    for (int p = 0; p < 3; ++p) s += ei[p] * Ap[p*VV*VV + idx];
    Asum[idx] = s;
  }
  if (idx >= 640 && idx < 768) zbuf[idx - 640] = 0.f;   // 512 B zero page
  int w = idx - 1024;
  if (w >= 0 && w < 18*OO*64){
    int kc = w >> 13;
    int r  = w & 8191;
    int o  = r >> 6;
    int j  = r & 63;
    int k  = kc >> 1;
    int i  = (kc & 1)*64 + j;
    Wq2[w] = f2b(tw[o*(OO*KT) + i*KT + k]);   // Wq2[kc][o][j] = tcn_w[o][i][k]
  }
  int w2 = idx - 148480;
  if (w2 >= 0 && w2 < OO*CC) gwb[w2] = f2b(gw[w2]);   // gwb[o][c]
  int w3 = idx - 156672;
  if (w3 >= 0 && w3 < OO*CC) rwb[w3] = f2b(rw[w3]);   // rwb[o][c]
}

// ---------------- gcn: MFMA agg (in-LDS) + MFMA GEMM: M=(t*25+v), N=128 o, K=64 c ----------------
// xg layout: [n][m=t*25+v][o].  No async16, LDS < 64 KB.
__global__ __launch_bounds__(256) void k_gcnm(const float* __restrict__ x, const float* __restrict__ Asum,
                                              const u16* __restrict__ gwb, const float* __restrict__ gb,
                                              u16* __restrict__ xg){
  __shared__ __align__(16) u16 xs[7*CC*34];     // 30464 B: [it][c][34], v padded to 32 (zeros)
  __shared__ __align__(16) u16 A_lds[128*64];   // 16 KB, XOR-swizzled granules
  __shared__ __align__(16) u16 B_lds[128*64];   // 16 KB, XOR-swizzled granules
  int bx = blockIdx.x;
  int n  = bx / MT;
  int m0 = (bx % MT) * 128;
  int t0 = m0 / VV, r0 = m0 % VV;
  int tid = threadIdx.x;
  int lane = tid & 63, wv = tid >> 6;
  int wm = (wv & 1) * 64, wo = (wv >> 1) * 64;
  int lr = lane & 15, lq = lane >> 4;

  // ---- stage B (gwb, 16 KB) with plain coalesced loads + swizzled ds_write ----
  {
    const u32* g32 = (const u32*)gwb;
    u32* b32 = (u32*)B_lds;
    for (int s = tid; s < 4096; s += 256){
      int row = s >> 5, col = s & 31;
      int g = col >> 2, c2 = col & 3;
      b32[row*32 + ((g ^ (row & 7))*4 + c2)] = g32[s];
    }
  }

  // ---- A_sum^T B-fragments in registers: bfw[wt], lane holds B[w=lr+16wt][v=lq*8+j] ----
  s8v bfw[2];
  #pragma unroll
  for (int wt = 0; wt < 2; ++wt){
    u16 tmp[8];
    int w = lr + 16*wt;
    #pragma unroll
    for (int j = 0; j < 8; ++j){
      int v = lq*8 + j;
      tmp[j] = (w < VV && v < VV) ? f2b(Asum[v*VV + w]) : (u16)0;
    }
    bfw[wt] = *(s8v*)tmp;
  }

  // ---- stage x slice: 7t x 64c x 32v bf16 (zero pad v>=25, t>=300) ----
  #pragma unroll
  for (int it = 0; it < 7; ++it){
    int t = t0 + it;
    bool ok = (t < TT);
    for (int s = tid; s < CC*32; s += 256){
      int c = s >> 5, v = s & 31;
      float val = (ok && v < VV) ? x[((size_t)(n*CC + c)*TT + t)*VV + v] : 0.f;
      xs[it*(CC*34) + c*34 + v] = f2b(val);
    }
  }
  __syncthreads();

  // ---- agg via MFMA: 56 tasks (7 it x 4 ct x 2 wt), D[c][w] -> A_lds[m=t*25+w-m0][c] ----
  #pragma unroll
  for (int tt = 0; tt < 14; ++tt){
    int tau = tt*4 + wv;
    int it = tau >> 3, ct = (tau >> 1) & 3, wt = tau & 1;
    s8v af = *(const s8v*)&xs[it*(CC*34) + (ct*16 + lr)*34 + lq*8];
    f4v d = (f4v)(0.f);
    d = __builtin_amdgcn_mfma_f32_16x16x32_bf16(af, bfw[wt], d, 0, 0, 0);
    int w  = lr + 16*wt;                 // D col
    int ml = it*VV + w - r0;             // local m row
    int cb = ct*16 + lq*4;               // D rows: 4 consecutive c
    if (w < VV && ml >= 0 && ml < 128){
      u16 pk[4];
      #pragma unroll
      for (int rg = 0; rg < 4; ++rg) pk[rg] = f2b(d[rg]);
      int g = cb >> 3;
      *(h4v*)&A_lds[ml*64 + (((g ^ (ml & 7))*8) + (cb & 7))] = *(h4v*)pk;
    }
  }
  __syncthreads();

  // ---- main GEMM: 64m x 64o per wave, K=64 (2 substeps) ----
  f4v acc[4][4];
  #pragma unroll
  for (int mi = 0; mi < 4; ++mi)
    #pragma unroll
    for (int ni = 0; ni < 4; ++ni) acc[mi][ni] = (f4v)(0.f);
  #pragma unroll
  for (int ks = 0; ks < 2; ++ks){
    int p = ((ks*4 + lq) ^ (lane & 7)) * 8;
    s8v af[4], bf[4];
    #pragma unroll
    for (int mi = 0; mi < 4; ++mi)
      af[mi] = *(const s8v*)&A_lds[(wm + mi*16 + lr)*64 + p];
    #pragma unroll
    for (int ni = 0; ni < 4; ++ni)
      bf[ni] = *(const s8v*)&B_lds[(wo + ni*16 + lr)*64 + p];
    #pragma unroll
    for (int mi = 0; mi < 4; ++mi)
      #pragma unroll
      for (int ni = 0; ni < 4; ++ni)
        acc[mi][ni] = __builtin_amdgcn_mfma_f32_16x16x32_bf16(af[mi], bf[ni], acc[mi][ni], 0, 0, 0);
  }

  float bias[4];
  #pragma unroll
  for (int ni = 0; ni < 4; ++ni) bias[ni] = gb[wo + ni*16 + lr];
  #pragma unroll
  for (int mi = 0; mi < 4; ++mi){
    int mr = m0 + wm + mi*16 + lq*4;
    #pragma unroll
    for (int ni = 0; ni < 4; ++ni){
      int o = wo + ni*16 + lr;
      #pragma unroll
      for (int rg = 0; rg < 4; ++rg){
        int m = mr + rg;
        if (m < MM)
          xg[((size_t)n*MM + m)*OO + o] = f2b(acc[mi][ni][rg] + bias[ni]);
      }
    }
  }
}

// ---------------- tcn as MFMA implicit GEMM: M=(t2*25+v), N=128 o, K=1152 ----------------
// xt layout: [n][m=t2*25+v][o]
__global__ __launch_bounds__(256) void k_tcnm(const u16* __restrict__ xg, const u16* __restrict__ Wq2,
                                              const float* __restrict__ tb, const u16* __restrict__ zbuf,
                                              u16* __restrict__ xt){
  __shared__ __align__(16) u16 A_lds[128*64];
  __shared__ __align__(16) u16 B_lds[128*64];
  int bx = blockIdx.x;
  int n  = bx / 30;
  int m0 = (bx % 30) * 128;
  int tid = threadIdx.x;
  int lane = tid & 63, wv = tid >> 6;
  int wm = (wv & 1) * 64, wo = (wv >> 1) * 64;
  int lr = lane & 15, lq = lane >> 4;

  int rlow = tid >> 3;
  int gsrc = (tid & 7) ^ (rlow & 7);
  int tid16 = tid * 16;
  int  tbse[4], vr[4]; bool vm[4];
  #pragma unroll
  for (int it = 0; it < 4; ++it){
    int m = m0 + it*32 + rlow;
    vm[it] = (m < M2);
    int t2 = m / VV, v = m - t2*VV;
    tbse[it] = 2*t2 - 4;
    vr[it] = v;
  }
  size_t basen = (size_t)n*MM*OO + (size_t)gsrc*8;

  f4v acc[4][4];
  #pragma unroll
  for (int mi = 0; mi < 4; ++mi)
    #pragma unroll
    for (int ni = 0; ni < 4; ++ni) acc[mi][ni] = (f4v)(0.f);

  for (int kc = 0; kc < 18; ++kc){
    int k  = kc >> 1;
    int i0 = (kc & 1) * 64;
    const u16* wbase = Wq2 + kc*8192;
    #pragma unroll
    for (int it = 0; it < 4; ++it){
      int t = tbse[it] + k;
      const u16* ga = (vm[it] && t >= 0 && t < TT)
                      ? xg + basen + (size_t)(t*VV + vr[it])*OO + i0
                      : zbuf;
      async16(ga, (char*)A_lds + it*4096 + tid16);
      async16(wbase + ((it*32 + rlow)*64 + gsrc*8), (char*)B_lds + it*4096 + tid16);
    }
    __syncthreads();
    #pragma unroll
    for (int ks = 0; ks < 2; ++ks){
      int p = ((ks*4 + lq) ^ (lane & 7)) * 8;
      s8v af[4], bf[4];
      #pragma unroll
      for (int mi = 0; mi < 4; ++mi)
        af[mi] = *(const s8v*)&A_lds[(wm + mi*16 + lr)*64 + p];
      #pragma unroll
      for (int ni = 0; ni < 4; ++ni)
        bf[ni] = *(const s8v*)&B_lds[(wo + ni*16 + lr)*64 + p];
      #pragma unroll
      for (int mi = 0; mi < 4; ++mi)
        #pragma unroll
        for (int ni = 0; ni < 4; ++ni)
          acc[mi][ni] = __builtin_amdgcn_mfma_f32_16x16x32_bf16(af[mi], bf[ni], acc[mi][ni], 0, 0, 0);
    }
    __syncthreads();
  }

  float bias[4];
  #pragma unroll
  for (int ni = 0; ni < 4; ++ni) bias[ni] = tb[wo + ni*16 + lr];
  #pragma unroll
  for (int mi = 0; mi < 4; ++mi){
    int mr = m0 + wm + mi*16 + lq*4;
    #pragma unroll
    for (int ni = 0; ni < 4; ++ni){
      int o = wo + ni*16 + lr;
      #pragma unroll
      for (int rg = 0; rg < 4; ++rg){
        int m = mr + rg;
        if (m < M2)
          xt[((size_t)n*M2 + m)*OO + o] = f2b(acc[mi][ni][rg] + bias[ni]);
      }
    }
  }
}

// ---------------- BN stats ----------------
__global__ __launch_bounds__(256) void k_stats1(const u16* __restrict__ xt, float* __restrict__ psum,
                                                float* __restrict__ psq){
  __shared__ float ls[256], lq[256];
  int tid = threadIdx.x;
  int o = tid & 127, rh = tid >> 7;
  int r0 = blockIdx.x * 480;
  float s = 0.f, q = 0.f;
  for (int r = r0 + rh; r < r0 + 480; r += 2){
    float f = b2f(xt[(size_t)r*OO + o]);
    s += f; q += f*f;
  }
  ls[tid] = s; lq[tid] = q;
  __syncthreads();
  if (tid < 128){
    psum[blockIdx.x*128 + o] = ls[tid] + ls[tid + 128];
    psq [blockIdx.x*128 + o] = lq[tid] + lq[tid + 128];
  }
}

__global__ __launch_bounds__(128) void k_stats2(const float* __restrict__ psum, const float* __restrict__ psq,
                                                const float* __restrict__ gamma, const float* __restrict__ beta,
                                                float* __restrict__ stats){
  int o = threadIdx.x;
  float s = 0.f, q = 0.f;
  for (int b = 0; b < 250; ++b){ s += psum[b*128 + o]; q += psq[b*128 + o]; }
  const float inv = 1.f / 120000.f;
  float mean = s * inv;
  float var  = q * inv - mean*mean;
  float sc = gamma[o] * rsqrtf(var + 1e-5f);
  stats[o]       = sc;
  stats[128 + o] = beta[o] - mean * sc;
}

// ---------------- res as MFMA implicit GEMM + BN + relu: M=(t2*25+v), N=128 o, K=64 c ----------------
// out[n][o][m] with m = t2*25+v  (== reference (N,O,T2,V))
__global__ __launch_bounds__(256) void k_resm(const float* __restrict__ x, const u16* __restrict__ rwb,
                                              const float* __restrict__ rb, const u16* __restrict__ xt,
                                              const float* __restrict__ stats, float* __restrict__ out){
  __shared__ __align__(16) u16 A_lds[128*64];   // 16 KB
  __shared__ __align__(16) u16 B_lds[128*64];   // 16 KB
  int bx = blockIdx.x;
  int n  = bx / 30;
  int m0 = (bx % 30) * 128;
  int t20 = m0 / VV, r0 = m0 % VV;
  int tid = threadIdx.x;
  int lane = tid & 63, wv = tid >> 6;
  int wm = (wv & 1) * 64, wo = (wv >> 1) * 64;
  int lr = lane & 15, lq = lane >> 4;

  {
    const u32* g32 = (const u32*)rwb;
    u32* b32 = (u32*)B_lds;
    for (int s = tid; s < 4096; s += 256){
      int row = s >> 5, col = s & 31;
      int g = col >> 2, c2 = col & 3;
      b32[row*32 + ((g ^ (row & 7))*4 + c2)] = g32[s];
    }
  }

  for (int idx = tid; idx < 7*CC*VV; idx += 256){
    int t2i = idx / (CC*VV);
    int rem = idx - t2i*(CC*VV);
    int c = rem / VV, v = rem - c*VV;
    int t2 = t20 + t2i;
    int ml = t2i*VV + v - r0;
    if (ml >= 0 && ml < 128){
      float val = (t2 < TO) ? x[((size_t)(n*CC + c)*TT + 2*t2)*VV + v] : 0.f;
      A_lds[ml*64 + (((c >> 3) ^ (ml & 7))*8 + (c & 7))] = f2b(val);
    }
  }
  __syncthreads();

  f4v acc[4][4];
  #pragma unroll
  for (int mi = 0; mi < 4; ++mi)
    #pragma unroll
    for (int ni = 0; ni < 4; ++ni) acc[mi][ni] = (f4v)(0.f);
  #pragma unroll
  for (int ks = 0; ks < 2; ++ks){
    int p = ((ks*4 + lq) ^ (lane & 7)) * 8;
    s8v af[4], bf[4];
    #pragma unroll
    for (int mi = 0; mi < 4; ++mi)
      af[mi] = *(const s8v*)&A_lds[(wm + mi*16 + lr)*64 + p];
    #pragma unroll
    for (int ni = 0; ni < 4; ++ni)
      bf[ni] = *(const s8v*)&B_lds[(wo + ni*16 + lr)*64 + p];
    #pragma unroll
    for (int mi = 0; mi < 4; ++mi)
      #pragma unroll
      for (int ni = 0; ni < 4; ++ni)
        acc[mi][ni] = __builtin_amdgcn_mfma_f32_16x16x32_bf16(af[mi], bf[ni], acc[mi][ni], 0, 0, 0);
  }

  float sc[4], sb[4], rr[4];
  #pragma unroll
  for (int ni = 0; ni < 4; ++ni){
    int o = wo + ni*16 + lr;
    sc[ni] = stats[o]; sb[ni] = stats[128 + o]; rr[ni] = rb[o];
  }
  #pragma unroll
  for (int mi = 0; mi < 4; ++mi){
    int mb = m0 + wm + mi*16 + lq*4;
    #pragma unroll
    for (int ni = 0; ni < 4; ++ni){
      int o = wo + ni*16 + lr;
      size_t xb = ((size_t)n*M2 + mb)*OO + o;
      size_t ob = ((size_t)(n*OO + o))*M2 + mb;
      if (mb + 3 < M2){
        float r0_ = fmaxf(sc[ni]*b2f(xt[xb])        + sb[ni] + acc[mi][ni][0] + rr[ni], 0.f);
        float r1_ = fmaxf(sc[ni]*b2f(xt[xb + OO])   + sb[ni] + acc[mi][ni][1] + rr[ni], 0.f);
        float r2_ = fmaxf(sc[ni]*b2f(xt[xb + 2*OO]) + sb[ni] + acc[mi][ni][2] + rr[ni], 0.f);
        float r3_ = fmaxf(sc[ni]*b2f(xt[xb + 3*OO]) + sb[ni] + acc[mi][ni][3] + rr[ni], 0.f);
        *(float2*)&out[ob]     = make_float2(r0_, r1_);
        *(float2*)&out[ob + 2] = make_float2(r2_, r3_);
      } else {
        #pragma unroll
        for (int rg = 0; rg < 4; ++rg){
          int m = mb + rg;
          if (m < M2){
            float r = sc[ni]*b2f(xt[xb + (size_t)rg*OO]) + sb[ni] + acc[mi][ni][rg] + rr[ni];
            out[ob + rg] = fmaxf(r, 0.f);
          }
        }
      }
    }
  }
}

extern "C" void kernel_launch(void* const* d_in, const int* in_sizes, int n_in,
                              void* d_out, int out_size, void* d_ws, size_t ws_size,
                              hipStream_t stream) {
  const float* x     = (const float*)d_in[0];
  const float* Ap    = (const float*)d_in[1];
  const float* ei    = (const float*)d_in[2];
  const float* gw    = (const float*)d_in[3];
  const float* gb    = (const float*)d_in[4];
  const float* tw    = (const float*)d_in[5];
  const float* tb    = (const float*)d_in[6];
  const float* gamma = (const float*)d_in[7];
  const float* beta  = (const float*)d_in[8];
  const float* rw    = (const float*)d_in[9];
  const float* rb    = (const float*)d_in[10];
  float* out = (float*)d_out;

  char* ws = (char*)d_ws;
  float* Asum  = (float*)ws;                      // 2500 B
  float* zbuf  = (float*)(ws + 2560);             // 512 B zero page
  u16*   Wq2   = (u16*)(ws + 4096);               // 294912 B
  float* psum  = (float*)(ws + 299008);           // 128000 B
  float* psq   = (float*)(ws + 427008);           // 128000 B
  float* stats = (float*)(ws + 555008);           // 1024 B
  u16*   gwb   = (u16*)(ws + 556032);             // 16384 B
  u16*   rwb   = (u16*)(ws + 572416);             // 16384 B
  u16*   xg    = (u16*)(ws + (1u<<20));           // 61,440,000 B [n][m=t*25+v][o] bf16
  u16*   xt    = (u16*)(ws + 62488576);           // 28,800,000 B [n][m=t2*25+v][o] bf16

  k_prep  <<<dim3(644),    dim3(256), 0, stream>>>(Ap, ei, tw, gw, rw, Asum, zbuf, Wq2, gwb, rwb);
  k_gcnm  <<<dim3(NB*MT),  dim3(256), 0, stream>>>(x, Asum, gwb, gb, xg);
  k_tcnm  <<<dim3(NB*30),  dim3(256), 0, stream>>>(xg, Wq2, tb, (const u16*)zbuf, xt);
  k_stats1<<<dim3(250),    dim3(256), 0, stream>>>(xt, psum, psq);
  k_stats2<<<dim3(1),      dim3(128), 0, stream>>>(psum, psq, gamma, beta, stats);
  k_resm  <<<dim3(NB*30),  dim3(256), 0, stream>>>(x, rwb, rb, xt, stats, out);
}

// Round 9
// 359.567 us; speedup vs baseline: 7.2258x; 1.2931x over previous
//
#include <hip/hip_runtime.h>
#include <hip/hip_bf16.h>

typedef unsigned short u16;
typedef unsigned int   u32;

#define NB 32
#define CC 64
#define TT 300
#define VV 25
#define OO 128
#define TO 150
#define KT 9
#define MM 7500          // T*V rows per n (gcn GEMM)
#define MT 59            // ceil(7500/128)
#define M2 3750          // T2*V rows per n (tcn/res GEMMs)

typedef short s8v  __attribute__((ext_vector_type(8)));
typedef float f4v  __attribute__((ext_vector_type(4)));
typedef u16  h4v  __attribute__((ext_vector_type(4)));

__device__ __forceinline__ float b2f(u16 u){
  union { u32 i; float f; } c; c.i = ((u32)u) << 16; return c.f;
}
__device__ __forceinline__ u16 f2b(float f){
  __hip_bfloat16 h = __float2bfloat16(f);
  return *reinterpret_cast<u16*>(&h);
}
__device__ __forceinline__ void async16(const void* g, void* l){
  __builtin_amdgcn_global_load_lds((const __attribute__((address_space(1))) u32*)g,
                                   (__attribute__((address_space(3))) u32*)l, 16, 0, 0);
}

// ---------------- prep: A_sum + zero-page + tcn_w repack + gcn_w/res_w bf16 ----------------
__global__ __launch_bounds__(256) void k_prep(const float* __restrict__ Ap, const float* __restrict__ ei,
                                              const float* __restrict__ tw, const float* __restrict__ gw,
                                              const float* __restrict__ rw,
                                              float* __restrict__ Asum, float* __restrict__ zbuf,
                                              u16* __restrict__ Wq2, u16* __restrict__ gwb,
                                              u16* __restrict__ rwb){
  int idx = blockIdx.x * 256 + threadIdx.x;
  if (idx < VV*VV){
    float s = 0.f;
    for (int p = 0; p < 3; ++p) s += ei[p] * Ap[p*VV*VV + idx];
    Asum[idx] = s;
  }
  if (idx >= 640 && idx < 768) zbuf[idx - 640] = 0.f;   // 512 B zero page
  int w = idx - 1024;
  if (w >= 0 && w < 18*OO*64){
    int kc = w >> 13;
    int r  = w & 8191;
    int o  = r >> 6;
    int j  = r & 63;
    int k  = kc >> 1;
    int i  = (kc & 1)*64 + j;
    Wq2[w] = f2b(tw[o*(OO*KT) + i*KT + k]);   // Wq2[kc][o][j] = tcn_w[o][i][k]
  }
  int w2 = idx - 148480;
  if (w2 >= 0 && w2 < OO*CC) gwb[w2] = f2b(gw[w2]);   // gwb[o][c]
  int w3 = idx - 156672;
  if (w3 >= 0 && w3 < OO*CC) rwb[w3] = f2b(rw[w3]);   // rwb[o][c]
}

// ---------------- gcn: register-direct MFMA agg + MFMA GEMM: M=(t*25+v), N=128 o, K=64 c ----------------
// xg layout: [n][m=t*25+v][o].  LDS = 32 KB; no x staging buffer.
__global__ __launch_bounds__(256, 4) void k_gcnm(const float* __restrict__ x, const float* __restrict__ Asum,
                                                 const u16* __restrict__ gwb, const float* __restrict__ gb,
                                                 u16* __restrict__ xg){
  __shared__ __align__(16) u16 A_lds[128*64];   // 16 KB, XOR-swizzled granules
  __shared__ __align__(16) u16 B_lds[128*64];   // 16 KB, XOR-swizzled granules
  int bx = blockIdx.x;
  int n  = bx / MT;
  int m0 = (bx % MT) * 128;
  int t0 = m0 / VV, r0 = m0 % VV;
  int tid = threadIdx.x;
  int lane = tid & 63, wv = tid >> 6;
  int wm = (wv & 1) * 64, wo = (wv >> 1) * 64;
  int lr = lane & 15, lq = lane >> 4;

  // ---- stage B (gwb, 16 KB) with plain coalesced loads + swizzled ds_write ----
  {
    const u32* g32 = (const u32*)gwb;
    u32* b32 = (u32*)B_lds;
    for (int s = tid; s < 4096; s += 256){
      int row = s >> 5, col = s & 31;
      int g = col >> 2, c2 = col & 3;
      b32[row*32 + ((g ^ (row & 7))*4 + c2)] = g32[s];
    }
  }

  // ---- A_sum^T B-fragments in registers: bfw[wt], lane holds B[w=lr+16wt][v=lq*8+j] ----
  s8v bfw[2];
  #pragma unroll
  for (int wt = 0; wt < 2; ++wt){
    u16 tmp[8];
    int w = lr + 16*wt;
    #pragma unroll
    for (int j = 0; j < 8; ++j){
      int v = lq*8 + j;
      tmp[j] = (w < VV && v < VV) ? f2b(Asum[v*VV + w]) : (u16)0;
    }
    bfw[wt] = *(s8v*)tmp;
  }

  // ---- agg via MFMA with register-direct A: 28 tasks (7 it x 4 ct) over 4 waves ----
  // lane (lr,lq): af = x[n][c=ct*16+lr][t0+it][v=lq*8..+7] (lq==3: only v=24 valid)
  int cbl = (wv & 3);   // placeholder to keep wv alive
  (void)cbl;
  #pragma unroll
  for (int tt = 0; tt < 7; ++tt){
    int tau = tt*4 + wv;
    int it = tau >> 2, ct = tau & 3;
    int t  = t0 + it;
    int c  = ct*16 + lr;
    const float* xp = x + ((size_t)(n*CC + c)*TT + t)*VV + lq*8;
    float4 xa = make_float4(0.f,0.f,0.f,0.f), xb = xa;
    float x24 = 0.f;
    if (t < TT){
      if (lq < 3){
        xa = *(const float4*)xp;
        xb = *(const float4*)(xp + 4);
      } else {
        x24 = xp[0];
      }
    }
    u16 pk[8];
    if (lq < 3){
      pk[0]=f2b(xa.x); pk[1]=f2b(xa.y); pk[2]=f2b(xa.z); pk[3]=f2b(xa.w);
      pk[4]=f2b(xb.x); pk[5]=f2b(xb.y); pk[6]=f2b(xb.z); pk[7]=f2b(xb.w);
    } else {
      pk[0]=f2b(x24); pk[1]=0; pk[2]=0; pk[3]=0; pk[4]=0; pk[5]=0; pk[6]=0; pk[7]=0;
    }
    s8v af = *(s8v*)pk;
    f4v d0 = (f4v)(0.f), d1 = (f4v)(0.f);
    d0 = __builtin_amdgcn_mfma_f32_16x16x32_bf16(af, bfw[0], d0, 0, 0, 0);
    d1 = __builtin_amdgcn_mfma_f32_16x16x32_bf16(af, bfw[1], d1, 0, 0, 0);
    // writes: D rows = 4 consecutive c (cb..cb+3), col w
    int cb = ct*16 + lq*4;
    int g  = cb >> 3, co = cb & 7;
    int ml0 = it*VV + lr - r0;                    // w = lr
    if (ml0 >= 0 && ml0 < 128){
      u16 q[4];
      #pragma unroll
      for (int rg = 0; rg < 4; ++rg) q[rg] = f2b(d0[rg]);
      *(h4v*)&A_lds[ml0*64 + ((g ^ (ml0 & 7))*8) + co] = *(h4v*)q;
    }
    int w1 = lr + 16;
    int ml1 = it*VV + w1 - r0;
    if (w1 < VV && ml1 >= 0 && ml1 < 128){
      u16 q[4];
      #pragma unroll
      for (int rg = 0; rg < 4; ++rg) q[rg] = f2b(d1[rg]);
      *(h4v*)&A_lds[ml1*64 + ((g ^ (ml1 & 7))*8) + co] = *(h4v*)q;
    }
  }
  __syncthreads();

  // ---- main GEMM: 64m x 64o per wave, K=64 (2 substeps) ----
  f4v acc[4][4];
  #pragma unroll
  for (int mi = 0; mi < 4; ++mi)
    #pragma unroll
    for (int ni = 0; ni < 4; ++ni) acc[mi][ni] = (f4v)(0.f);
  #pragma unroll
  for (int ks = 0; ks < 2; ++ks){
    int p = ((ks*4 + lq) ^ (lane & 7)) * 8;
    s8v af[4], bf[4];
    #pragma unroll
    for (int mi = 0; mi < 4; ++mi)
      af[mi] = *(const s8v*)&A_lds[(wm + mi*16 + lr)*64 + p];
    #pragma unroll
    for (int ni = 0; ni < 4; ++ni)
      bf[ni] = *(const s8v*)&B_lds[(wo + ni*16 + lr)*64 + p];
    #pragma unroll
    for (int mi = 0; mi < 4; ++mi)
      #pragma unroll
      for (int ni = 0; ni < 4; ++ni)
        acc[mi][ni] = __builtin_amdgcn_mfma_f32_16x16x32_bf16(af[mi], bf[ni], acc[mi][ni], 0, 0, 0);
  }

  float bias[4];
  #pragma unroll
  for (int ni = 0; ni < 4; ++ni) bias[ni] = gb[wo + ni*16 + lr];
  #pragma unroll
  for (int mi = 0; mi < 4; ++mi){
    int mr = m0 + wm + mi*16 + lq*4;
    #pragma unroll
    for (int ni = 0; ni < 4; ++ni){
      int o = wo + ni*16 + lr;
      #pragma unroll
      for (int rg = 0; rg < 4; ++rg){
        int m = mr + rg;
        if (m < MM)
          xg[((size_t)n*MM + m)*OO + o] = f2b(acc[mi][ni][rg] + bias[ni]);
      }
    }
  }
}

// ---------------- tcn as MFMA implicit GEMM: M=(t2*25+v), N=128 o, K=1152 ----------------
// xt layout: [n][m=t2*25+v][o]
__global__ __launch_bounds__(256) void k_tcnm(const u16* __restrict__ xg, const u16* __restrict__ Wq2,
                                              const float* __restrict__ tb, const u16* __restrict__ zbuf,
                                              u16* __restrict__ xt){
  __shared__ __align__(16) u16 A_lds[128*64];
  __shared__ __align__(16) u16 B_lds[128*64];
  int bx = blockIdx.x;
  int n  = bx / 30;
  int m0 = (bx % 30) * 128;
  int tid = threadIdx.x;
  int lane = tid & 63, wv = tid >> 6;
  int wm = (wv & 1) * 64, wo = (wv >> 1) * 64;
  int lr = lane & 15, lq = lane >> 4;

  int rlow = tid >> 3;
  int gsrc = (tid & 7) ^ (rlow & 7);
  int tid16 = tid * 16;
  int  tbse[4], vr[4]; bool vm[4];
  #pragma unroll
  for (int it = 0; it < 4; ++it){
    int m = m0 + it*32 + rlow;
    vm[it] = (m < M2);
    int t2 = m / VV, v = m - t2*VV;
    tbse[it] = 2*t2 - 4;
    vr[it] = v;
  }
  size_t basen = (size_t)n*MM*OO + (size_t)gsrc*8;

  f4v acc[4][4];
  #pragma unroll
  for (int mi = 0; mi < 4; ++mi)
    #pragma unroll
    for (int ni = 0; ni < 4; ++ni) acc[mi][ni] = (f4v)(0.f);

  for (int kc = 0; kc < 18; ++kc){
    int k  = kc >> 1;
    int i0 = (kc & 1) * 64;
    const u16* wbase = Wq2 + kc*8192;
    #pragma unroll
    for (int it = 0; it < 4; ++it){
      int t = tbse[it] + k;
      const u16* ga = (vm[it] && t >= 0 && t < TT)
                      ? xg + basen + (size_t)(t*VV + vr[it])*OO + i0
                      : zbuf;
      async16(ga, (char*)A_lds + it*4096 + tid16);
      async16(wbase + ((it*32 + rlow)*64 + gsrc*8), (char*)B_lds + it*4096 + tid16);
    }
    __syncthreads();
    #pragma unroll
    for (int ks = 0; ks < 2; ++ks){
      int p = ((ks*4 + lq) ^ (lane & 7)) * 8;
      s8v af[4], bf[4];
      #pragma unroll
      for (int mi = 0; mi < 4; ++mi)
        af[mi] = *(const s8v*)&A_lds[(wm + mi*16 + lr)*64 + p];
      #pragma unroll
      for (int ni = 0; ni < 4; ++ni)
        bf[ni] = *(const s8v*)&B_lds[(wo + ni*16 + lr)*64 + p];
      #pragma unroll
      for (int mi = 0; mi < 4; ++mi)
        #pragma unroll
        for (int ni = 0; ni < 4; ++ni)
          acc[mi][ni] = __builtin_amdgcn_mfma_f32_16x16x32_bf16(af[mi], bf[ni], acc[mi][ni], 0, 0, 0);
    }
    __syncthreads();
  }

  float bias[4];
  #pragma unroll
  for (int ni = 0; ni < 4; ++ni) bias[ni] = tb[wo + ni*16 + lr];
  #pragma unroll
  for (int mi = 0; mi < 4; ++mi){
    int mr = m0 + wm + mi*16 + lq*4;
    #pragma unroll
    for (int ni = 0; ni < 4; ++ni){
      int o = wo + ni*16 + lr;
      #pragma unroll
      for (int rg = 0; rg < 4; ++rg){
        int m = mr + rg;
        if (m < M2)
          xt[((size_t)n*M2 + m)*OO + o] = f2b(acc[mi][ni][rg] + bias[ni]);
      }
    }
  }
}

// ---------------- BN stats ----------------
__global__ __launch_bounds__(256) void k_stats1(const u16* __restrict__ xt, float* __restrict__ psum,
                                                float* __restrict__ psq){
  __shared__ float ls[256], lq[256];
  int tid = threadIdx.x;
  int o = tid & 127, rh = tid >> 7;
  int r0 = blockIdx.x * 480;
  float s = 0.f, q = 0.f;
  for (int r = r0 + rh; r < r0 + 480; r += 2){
    float f = b2f(xt[(size_t)r*OO + o]);
    s += f; q += f*f;
  }
  ls[tid] = s; lq[tid] = q;
  __syncthreads();
  if (tid < 128){
    psum[blockIdx.x*128 + o] = ls[tid] + ls[tid + 128];
    psq [blockIdx.x*128 + o] = lq[tid] + lq[tid + 128];
  }
}

__global__ __launch_bounds__(128) void k_stats2(const float* __restrict__ psum, const float* __restrict__ psq,
                                                const float* __restrict__ gamma, const float* __restrict__ beta,
                                                float* __restrict__ stats){
  int o = threadIdx.x;
  float s = 0.f, q = 0.f;
  for (int b = 0; b < 250; ++b){ s += psum[b*128 + o]; q += psq[b*128 + o]; }
  const float inv = 1.f / 120000.f;
  float mean = s * inv;
  float var  = q * inv - mean*mean;
  float sc = gamma[o] * rsqrtf(var + 1e-5f);
  stats[o]       = sc;
  stats[128 + o] = beta[o] - mean * sc;
}

// ---------------- res as MFMA implicit GEMM + BN + relu: M=(t2*25+v), N=128 o, K=64 c ----------------
// out[n][o][m] with m = t2*25+v  (== reference (N,O,T2,V))
__global__ __launch_bounds__(256) void k_resm(const float* __restrict__ x, const u16* __restrict__ rwb,
                                              const float* __restrict__ rb, const u16* __restrict__ xt,
                                              const float* __restrict__ stats, float* __restrict__ out){
  __shared__ __align__(16) u16 A_lds[128*64];   // 16 KB
  __shared__ __align__(16) u16 B_lds[128*64];   // 16 KB
  int bx = blockIdx.x;
  int n  = bx / 30;
  int m0 = (bx % 30) * 128;
  int t20 = m0 / VV, r0 = m0 % VV;
  int tid = threadIdx.x;
  int lane = tid & 63, wv = tid >> 6;
  int wm = (wv & 1) * 64, wo = (wv >> 1) * 64;
  int lr = lane & 15, lq = lane >> 4;

  {
    const u32* g32 = (const u32*)rwb;
    u32* b32 = (u32*)B_lds;
    for (int s = tid; s < 4096; s += 256){
      int row = s >> 5, col = s & 31;
      int g = col >> 2, c2 = col & 3;
      b32[row*32 + ((g ^ (row & 7))*4 + c2)] = g32[s];
    }
  }

  for (int idx = tid; idx < 7*CC*VV; idx += 256){
    int t2i = idx / (CC*VV);
    int rem = idx - t2i*(CC*VV);
    int c = rem / VV, v = rem - c*VV;
    int t2 = t20 + t2i;
    int ml = t2i*VV + v - r0;
    if (ml >= 0 && ml < 128){
      float val = (t2 < TO) ? x[((size_t)(n*CC + c)*TT + 2*t2)*VV + v] : 0.f;
      A_lds[ml*64 + (((c >> 3) ^ (ml & 7))*8 + (c & 7))] = f2b(val);
    }
  }
  __syncthreads();

  f4v acc[4][4];
  #pragma unroll
  for (int mi = 0; mi < 4; ++mi)
    #pragma unroll
    for (int ni = 0; ni < 4; ++ni) acc[mi][ni] = (f4v)(0.f);
  #pragma unroll
  for (int ks = 0; ks < 2; ++ks){
    int p = ((ks*4 + lq) ^ (lane & 7)) * 8;
    s8v af[4], bf[4];
    #pragma unroll
    for (int mi = 0; mi < 4; ++mi)
      af[mi] = *(const s8v*)&A_lds[(wm + mi*16 + lr)*64 + p];
    #pragma unroll
    for (int ni = 0; ni < 4; ++ni)
      bf[ni] = *(const s8v*)&B_lds[(wo + ni*16 + lr)*64 + p];
    #pragma unroll
    for (int mi = 0; mi < 4; ++mi)
      #pragma unroll
      for (int ni = 0; ni < 4; ++ni)
        acc[mi][ni] = __builtin_amdgcn_mfma_f32_16x16x32_bf16(af[mi], bf[ni], acc[mi][ni], 0, 0, 0);
  }

  float sc[4], sb[4], rr[4];
  #pragma unroll
  for (int ni = 0; ni < 4; ++ni){
    int o = wo + ni*16 + lr;
    sc[ni] = stats[o]; sb[ni] = stats[128 + o]; rr[ni] = rb[o];
  }
  #pragma unroll
  for (int mi = 0; mi < 4; ++mi){
    int mb = m0 + wm + mi*16 + lq*4;
    #pragma unroll
    for (int ni = 0; ni < 4; ++ni){
      int o = wo + ni*16 + lr;
      size_t xb = ((size_t)n*M2 + mb)*OO + o;
      size_t ob = ((size_t)(n*OO + o))*M2 + mb;
      if (mb + 3 < M2){
        float r0_ = fmaxf(sc[ni]*b2f(xt[xb])        + sb[ni] + acc[mi][ni][0] + rr[ni], 0.f);
        float r1_ = fmaxf(sc[ni]*b2f(xt[xb + OO])   + sb[ni] + acc[mi][ni][1] + rr[ni], 0.f);
        float r2_ = fmaxf(sc[ni]*b2f(xt[xb + 2*OO]) + sb[ni] + acc[mi][ni][2] + rr[ni], 0.f);
        float r3_ = fmaxf(sc[ni]*b2f(xt[xb + 3*OO]) + sb[ni] + acc[mi][ni][3] + rr[ni], 0.f);
        *(float2*)&out[ob]     = make_float2(r0_, r1_);
        *(float2*)&out[ob + 2] = make_float2(r2_, r3_);
      } else {
        #pragma unroll
        for (int rg = 0; rg < 4; ++rg){
          int m = mb + rg;
          if (m < M2){
            float r = sc[ni]*b2f(xt[xb + (size_t)rg*OO]) + sb[ni] + acc[mi][ni][rg] + rr[ni];
            out[ob + rg] = fmaxf(r, 0.f);
          }
        }
      }
    }
  }
}

extern "C" void kernel_launch(void* const* d_in, const int* in_sizes, int n_in,
                              void* d_out, int out_size, void* d_ws, size_t ws_size,
                              hipStream_t stream) {
  const float* x     = (const float*)d_in[0];
  const float* Ap    = (const float*)d_in[1];
  const float* ei    = (const float*)d_in[2];
  const float* gw    = (const float*)d_in[3];
  const float* gb    = (const float*)d_in[4];
  const float* tw    = (const float*)d_in[5];
  const float* tb    = (const float*)d_in[6];
  const float* gamma = (const float*)d_in[7];
  const float* beta  = (const float*)d_in[8];
  const float* rw    = (const float*)d_in[9];
  const float* rb    = (const float*)d_in[10];
  float* out = (float*)d_out;

  char* ws = (char*)d_ws;
  float* Asum  = (float*)ws;                      // 2500 B
  float* zbuf  = (float*)(ws + 2560);             // 512 B zero page
  u16*   Wq2   = (u16*)(ws + 4096);               // 294912 B
  float* psum  = (float*)(ws + 299008);           // 128000 B
  float* psq   = (float*)(ws + 427008);           // 128000 B
  float* stats = (float*)(ws + 555008);           // 1024 B
  u16*   gwb   = (u16*)(ws + 556032);             // 16384 B
  u16*   rwb   = (u16*)(ws + 572416);             // 16384 B
  u16*   xg    = (u16*)(ws + (1u<<20));           // 61,440,000 B [n][m=t*25+v][o] bf16
  u16*   xt    = (u16*)(ws + 62488576);           // 28,800,000 B [n][m=t2*25+v][o] bf16

  k_prep  <<<dim3(644),    dim3(256), 0, stream>>>(Ap, ei, tw, gw, rw, Asum, zbuf, Wq2, gwb, rwb);
  k_gcnm  <<<dim3(NB*MT),  dim3(256), 0, stream>>>(x, Asum, gwb, gb, xg);
  k_tcnm  <<<dim3(NB*30),  dim3(256), 0, stream>>>(xg, Wq2, tb, (const u16*)zbuf, xt);
  k_stats1<<<dim3(250),    dim3(256), 0, stream>>>(xt, psum, psq);
  k_stats2<<<dim3(1),      dim3(128), 0, stream>>>(psum, psq, gamma, beta, stats);
  k_resm  <<<dim3(NB*30),  dim3(256), 0, stream>>>(x, rwb, rb, xt, stats, out);
}